// Round 1
// baseline (3704.011 us; speedup 1.0000x reference)
//
#include <hip/hip_runtime.h>
#include <hip/hip_bf16.h>

typedef short short8 __attribute__((ext_vector_type(8)));
typedef float floatx4 __attribute__((ext_vector_type(4)));

#define B_ 64
#define L_ 196
#define T_ 31
#define PRED_ 19840000ULL

__device__ __forceinline__ float bf2f(unsigned short u){
  union { unsigned int i; float f; } v; v.i = ((unsigned int)u)<<16; return v.f;
}
__device__ __forceinline__ float sigm(float x){ return 1.0f/(1.0f+__expf(-x)); }

// ---------------- cast f32 -> bf16 (vector x4) ----------------
__global__ __launch_bounds__(256) void k_cast(const float* __restrict__ src,
                                              __hip_bfloat16* __restrict__ dst, int n4){
  int i = blockIdx.x*256 + threadIdx.x;
  if (i < n4){
    const float4 v = *(const float4*)(src + (size_t)i*4);
    size_t o = (size_t)i*4;
    dst[o+0] = __float2bfloat16(v.x);
    dst[o+1] = __float2bfloat16(v.y);
    dst[o+2] = __float2bfloat16(v.z);
    dst[o+3] = __float2bfloat16(v.w);
  }
}

// ---------------- tiled transpose: src (Kin x Nin) -> dst[n][k], row stride S --------
__global__ __launch_bounds__(1024) void k_trans_f32(const float* __restrict__ src,
    float* __restrict__ dst, int Kin, int Nin, int S){
  __shared__ float tile[32][33];
  int n0 = blockIdx.x*32, k0 = blockIdx.y*32;
  int x = threadIdx.x & 31, y = threadIdx.x >> 5;
  int k = k0 + y, nn = n0 + x;
  tile[y][x] = (k < Kin && nn < Nin) ? src[(size_t)k*Nin + nn] : 0.0f;
  __syncthreads();
  int n2 = n0 + y, k2 = k0 + x;
  if (n2 < Nin && k2 < Kin) dst[(size_t)n2*S + k2] = tile[x][y];
}

__global__ __launch_bounds__(1024) void k_trans_bf16(const float* __restrict__ src,
    __hip_bfloat16* __restrict__ dst, int Kin, int Nin, int S, int Rtot){
  __shared__ float tile[32][33];
  int n0 = blockIdx.x*32, k0 = blockIdx.y*32;
  int x = threadIdx.x & 31, y = threadIdx.x >> 5;
  int k = k0 + y, nn = n0 + x;
  tile[y][x] = (k < Kin && nn < Nin) ? src[(size_t)k*Nin + nn] : 0.0f;
  __syncthreads();
  int n2 = n0 + y, k2 = k0 + x;
  if (n2 < Rtot && k2 < Kin) dst[(size_t)n2*S + k2] = __float2bfloat16(tile[x][y]);
}

// ---------------- embedding gather: E_T[t][m][b] f32, E_row[(t*64+b)][m] bf16 -------
__global__ __launch_bounds__(512) void k_emb(const int* __restrict__ captions,
    const float* __restrict__ emb, float* __restrict__ ET, __hip_bfloat16* __restrict__ Erow){
  int tb = blockIdx.x; int t = tb >> 6; int b = tb & 63; int m = threadIdx.x;
  int cap = captions[b*32 + t];
  float v = emb[(size_t)cap*512 + m];
  ET[((size_t)t*512 + m)*64 + b] = v;
  Erow[((size_t)(t*64 + b))*512 + m] = __float2bfloat16(v);
}

// ---------------- init h0/c0 (one block per b) ----------------
__global__ __launch_bounds__(512) void k_init(const float* __restrict__ enc,
    const float* __restrict__ Whi, const float* __restrict__ bhi,
    const float* __restrict__ Wci, const float* __restrict__ bci,
    float* __restrict__ hT, float* __restrict__ cT){
  int b = blockIdx.x; int d = threadIdx.x;
  __shared__ float ms[512];
  const float* eb = enc + (size_t)b*L_*512;
  float s = 0.f;
  for (int l = 0; l < L_; l++) s += eb[(size_t)l*512 + d];
  ms[d] = s * (1.0f/196.0f);
  __syncthreads();
  float a1 = bhi[d], a2 = bci[d];
  #pragma unroll 4
  for (int k = 0; k < 512; k++){
    float mv = ms[k];
    a1 += mv * Whi[(size_t)k*512 + d];
    a2 += mv * Wci[(size_t)k*512 + d];
  }
  hT[d*64 + b] = tanhf(a1);
  cT[d*64 + b] = tanhf(a2);
}

// ---------------- phase1: ph1_T[n][b] = [att2 | beta_pre | h@W_hh], n in [0,3072) ----
__global__ __launch_bounds__(256) void k_phase1(const float* __restrict__ hT,
    const float* __restrict__ W1T, const float* __restrict__ b_da,
    const float* __restrict__ b_fb, float* __restrict__ ph1T){
  int lane = threadIdx.x & 63;
  int gw = (blockIdx.x << 2) + (threadIdx.x >> 6);
  gw = __builtin_amdgcn_readfirstlane(gw);
  const float* __restrict__ wp0 = W1T + (size_t)(gw*4+0)*512;
  const float* __restrict__ wp1 = W1T + (size_t)(gw*4+1)*512;
  const float* __restrict__ wp2 = W1T + (size_t)(gw*4+2)*512;
  const float* __restrict__ wp3 = W1T + (size_t)(gw*4+3)*512;
  float a0=0.f, a1=0.f, a2=0.f, a3=0.f;
  #pragma unroll 8
  for (int k = 0; k < 512; k++){
    float h = hT[k*64 + lane];
    a0 += h * wp0[k]; a1 += h * wp1[k]; a2 += h * wp2[k]; a3 += h * wp3[k];
  }
  float acc[4] = {a0, a1, a2, a3};
  #pragma unroll
  for (int c = 0; c < 4; c++){
    int n = gw*4 + c;
    float bias = (n < 512) ? b_da[n] : ((n < 1024) ? b_fb[n-512] : 0.f);
    ph1T[(size_t)n*64 + lane] = acc[c] + bias;
  }
}

// ---------------- attention (one block per b): e -> softmax -> z, writes alpha out ----
__global__ __launch_bounds__(256) void k_attn(const float* __restrict__ enc,
    const __hip_bfloat16* __restrict__ att1, const float* __restrict__ ph1T,
    const float* __restrict__ wfa, const int* __restrict__ caplen, int t,
    float* __restrict__ zT, __hip_bfloat16* __restrict__ HZ, float* __restrict__ outAlpha){
  int b = blockIdx.x;
  int tid = threadIdx.x; int lane = tid & 63; int w = tid >> 6;
  __shared__ float es[196];
  __shared__ float MS[2];
  float a2r[8], wfr[8];
  #pragma unroll
  for (int u = 0; u < 8; u++){
    int a = lane*8 + u;
    a2r[u] = ph1T[(size_t)a*64 + b];
    wfr[u] = wfa[a];
  }
  const unsigned short* at1 = (const unsigned short*)att1 + (size_t)b*L_*512;
  for (int l = w; l < L_; l += 4){
    short8 s = *(const short8*)(at1 + (size_t)l*512 + lane*8);
    float e = 0.f;
    #pragma unroll
    for (int u = 0; u < 8; u++){
      float v = bf2f((unsigned short)s[u]) + a2r[u];
      v = fmaxf(v, 0.f);
      e += v * wfr[u];
    }
    #pragma unroll
    for (int off = 32; off; off >>= 1) e += __shfl_xor(e, off, 64);
    if (lane == 0) es[l] = e;
  }
  __syncthreads();
  if (w == 0){
    float v0 = es[lane], v1 = es[lane+64], v2 = es[lane+128];
    float v3 = (lane < 4) ? es[lane+192] : -1e30f;
    float m = fmaxf(fmaxf(v0, v1), fmaxf(v2, v3));
    #pragma unroll
    for (int off = 32; off; off >>= 1) m = fmaxf(m, __shfl_xor(m, off, 64));
    float sm = __expf(v0-m) + __expf(v1-m) + __expf(v2-m) + ((lane < 4) ? __expf(v3-m) : 0.f);
    #pragma unroll
    for (int off = 32; off; off >>= 1) sm += __shfl_xor(sm, off, 64);
    if (lane == 0){ MS[0] = m; MS[1] = sm; }
  }
  __syncthreads();
  float mx = MS[0]; float inv = 1.0f / MS[1];
  int dl = caplen[b] - 1;
  float maskf = (t < dl) ? 1.f : 0.f;
  float* oa = outAlpha + ((size_t)b*T_ + t)*L_;
  for (int l = tid; l < L_; l += 256){
    float al = __expf(es[l] - mx) * inv;
    es[l] = al;
    oa[l] = al * maskf;
  }
  __syncthreads();
  int d0 = tid, d1 = tid + 256;
  const float* eb = enc + (size_t)b*L_*512;
  float z0 = 0.f, z1 = 0.f;
  #pragma unroll 2
  for (int l = 0; l < L_; l++){
    float al = es[l];
    z0 += al * eb[(size_t)l*512 + d0];
    z1 += al * eb[(size_t)l*512 + d1];
  }
  float bp0 = ph1T[(size_t)(512+d0)*64 + b];
  float bp1 = ph1T[(size_t)(512+d1)*64 + b];
  z0 *= sigm(bp0);
  z1 *= sigm(bp1);
  zT[d0*64 + b] = z0;
  zT[d1*64 + b] = z1;
  __hip_bfloat16* hz = HZ + ((size_t)(t*64 + b))*1024 + 512;
  hz[d0] = __float2bfloat16(z0);
  hz[d1] = __float2bfloat16(z1);
}

// ---------------- gates GEMM + LSTM pointwise ----------------
__global__ __launch_bounds__(256) void k_gates(const float* __restrict__ ET,
    const float* __restrict__ zT, const float* __restrict__ WihT,
    const float* __restrict__ ph1T, const float* __restrict__ b_ih,
    const float* __restrict__ b_hh, const int* __restrict__ caplen, int t,
    float* __restrict__ hT, float* __restrict__ cT, __hip_bfloat16* __restrict__ HZ){
  int tid = threadIdx.x; int lane = tid & 63; int w = tid >> 6;
  int n = blockIdx.x*2 + (w >> 1);
  n = __builtin_amdgcn_readfirstlane(n);
  int kh = w & 1;
  const float* __restrict__ x0 = (kh == 0) ? (ET + (size_t)t*512*64) : zT;
  const float* __restrict__ wq0 = WihT + ((size_t)(0*512 + n))*1024 + kh*512;
  const float* __restrict__ wq1 = WihT + ((size_t)(1*512 + n))*1024 + kh*512;
  const float* __restrict__ wq2 = WihT + ((size_t)(2*512 + n))*1024 + kh*512;
  const float* __restrict__ wq3 = WihT + ((size_t)(3*512 + n))*1024 + kh*512;
  float g0=0.f, g1=0.f, g2=0.f, g3=0.f;
  #pragma unroll 8
  for (int k = 0; k < 512; k++){
    float x = x0[k*64 + lane];
    g0 += x * wq0[k]; g1 += x * wq1[k]; g2 += x * wq2[k]; g3 += x * wq3[k];
  }
  __shared__ float gs[4][4][64];
  gs[w][0][lane] = g0; gs[w][1][lane] = g1; gs[w][2][lane] = g2; gs[w][3][lane] = g3;
  __syncthreads();
  if (kh == 0){
    int wo = w + 1;
    float gi = g0 + gs[wo][0][lane] + ph1T[(size_t)(1024 + 0*512 + n)*64 + lane] + b_ih[0*512+n] + b_hh[0*512+n];
    float gf = g1 + gs[wo][1][lane] + ph1T[(size_t)(1024 + 1*512 + n)*64 + lane] + b_ih[1*512+n] + b_hh[1*512+n];
    float gg = g2 + gs[wo][2][lane] + ph1T[(size_t)(1024 + 2*512 + n)*64 + lane] + b_ih[2*512+n] + b_hh[2*512+n];
    float go = g3 + gs[wo][3][lane] + ph1T[(size_t)(1024 + 3*512 + n)*64 + lane] + b_ih[3*512+n] + b_hh[3*512+n];
    float i_ = sigm(gi), f_ = sigm(gf), c_in = tanhf(gg), o_ = sigm(go);
    float c_old = cT[n*64 + lane];
    float c_new = f_ * c_old + i_ * c_in;
    float h_new = o_ * tanhf(c_new);
    float h_old = hT[n*64 + lane];
    int dl = caplen[lane] - 1;
    bool m = (t < dl);
    hT[n*64 + lane] = m ? h_new : h_old;
    cT[n*64 + lane] = m ? c_new : c_old;
    HZ[((size_t)(t*64 + lane))*1024 + n] = __float2bfloat16(h_new);
  }
}

// ---------------- MFMA bf16 GEMM: C(64x64 tiles) = A(MxK) @ Bt(NxK)^T ----------------
// mode 0: att1   -> outB bf16 = acc + bias1[c]
// mode 1: U      -> outB bf16 = acc + bias1[c] + bias2[c] + Erow[r][c]
// mode 2: logits -> outF f32  = mask(t<dec_len) * (acc + bias1[c]) at [b][t][c]
__global__ __launch_bounds__(256) void k_gemm(const __hip_bfloat16* __restrict__ Abf,
    const __hip_bfloat16* __restrict__ Bt, int K, int mode, int Nreal,
    const float* __restrict__ bias1, const float* __restrict__ bias2,
    const __hip_bfloat16* __restrict__ Erow, const int* __restrict__ caplen,
    __hip_bfloat16* __restrict__ outB, float* __restrict__ outF){
  int lane = threadIdx.x & 63; int wv = threadIdx.x >> 6;
  int wr = wv >> 1, wc = wv & 1;
  int r0 = blockIdx.y*64 + wr*32;
  int c0 = blockIdx.x*64 + wc*32;
  int l15 = lane & 15, lg = lane >> 4;
  const short* Ap = (const short*)Abf;
  const short* Bp = (const short*)Bt;
  floatx4 acc00 = {0,0,0,0}, acc01 = {0,0,0,0}, acc10 = {0,0,0,0}, acc11 = {0,0,0,0};
  size_t ar0 = (size_t)(r0 + l15)*K + lg*8;
  size_t ar1 = ar0 + (size_t)16*K;
  size_t br0 = (size_t)(c0 + l15)*K + lg*8;
  size_t br1 = br0 + (size_t)16*K;
  #pragma unroll 4
  for (int k0 = 0; k0 < K; k0 += 32){
    short8 av0 = *(const short8*)(Ap + ar0 + k0);
    short8 av1 = *(const short8*)(Ap + ar1 + k0);
    short8 bv0 = *(const short8*)(Bp + br0 + k0);
    short8 bv1 = *(const short8*)(Bp + br1 + k0);
    acc00 = __builtin_amdgcn_mfma_f32_16x16x32_bf16(av0, bv0, acc00, 0, 0, 0);
    acc01 = __builtin_amdgcn_mfma_f32_16x16x32_bf16(av0, bv1, acc01, 0, 0, 0);
    acc10 = __builtin_amdgcn_mfma_f32_16x16x32_bf16(av1, bv0, acc10, 0, 0, 0);
    acc11 = __builtin_amdgcn_mfma_f32_16x16x32_bf16(av1, bv1, acc11, 0, 0, 0);
  }
  floatx4 accs[2][2] = {{acc00, acc01}, {acc10, acc11}};
  #pragma unroll
  for (int i = 0; i < 2; i++){
    #pragma unroll
    for (int j = 0; j < 2; j++){
      #pragma unroll
      for (int v = 0; v < 4; v++){
        int r = r0 + 16*i + lg*4 + v;
        int c = c0 + 16*j + l15;
        float val = accs[i][j][v];
        if (mode == 0){
          outB[(size_t)r*512 + c] = __float2bfloat16(val + bias1[c]);
        } else if (mode == 1){
          float e = bf2f(((const unsigned short*)Erow)[(size_t)r*512 + c]);
          outB[(size_t)r*512 + c] = __float2bfloat16(val + bias1[c] + bias2[c] + e);
        } else {
          if (c < Nreal){
            int t = r >> 6, b = r & 63;
            float mf = (t < caplen[b] - 1) ? 1.f : 0.f;
            outF[((size_t)b*T_ + t)*10000 + c] = (val + bias1[c]) * mf;
          }
        }
      }
    }
  }
}

extern "C" void kernel_launch(void* const* d_in, const int* in_sizes, int n_in,
                              void* d_out, int out_size, void* d_ws, size_t ws_size,
                              hipStream_t stream){
  (void)in_sizes; (void)n_in; (void)out_size; (void)ws_size;
  const float* enc   = (const float*)d_in[0];
  const int* captions = (const int*)d_in[1];
  const int* caplen  = (const int*)d_in[2];
  const float* emb   = (const float*)d_in[3];
  const float* W_ea  = (const float*)d_in[4];  const float* b_ea = (const float*)d_in[5];
  const float* W_da  = (const float*)d_in[6];  const float* b_da = (const float*)d_in[7];
  const float* w_fa  = (const float*)d_in[8];  /* b_fa (d_in[9]) cancels in softmax */
  const float* W_hi  = (const float*)d_in[10]; const float* b_hi = (const float*)d_in[11];
  const float* W_ci  = (const float*)d_in[12]; const float* b_ci = (const float*)d_in[13];
  const float* W_ih  = (const float*)d_in[14]; const float* W_hh = (const float*)d_in[15];
  const float* b_ih  = (const float*)d_in[16]; const float* b_hh = (const float*)d_in[17];
  const float* W_fb  = (const float*)d_in[18]; const float* b_fb = (const float*)d_in[19];
  const float* W_lh  = (const float*)d_in[20]; const float* b_lh = (const float*)d_in[21];
  const float* W_lz  = (const float*)d_in[22]; const float* b_lz = (const float*)d_in[23];
  const float* W_lo  = (const float*)d_in[24]; const float* b_lo = (const float*)d_in[25];
  float* out = (float*)d_out;

  char* p = (char*)d_ws;
  auto alloc = [&](size_t bytes){ char* r = p; p += bytes; return r; };
  __hip_bfloat16* enc_bf  = (__hip_bfloat16*)alloc(12845056); // 64*196*512 bf16
  __hip_bfloat16* att1_bf = (__hip_bfloat16*)alloc(12845056); // 64*196*512 bf16
  __hip_bfloat16* WeaT    = (__hip_bfloat16*)alloc(524288);   // 512x512 bf16
  float*          W1T     = (float*)alloc(6291456);           // 3072x512 f32
  float*          WihT    = (float*)alloc(8388608);           // 2048x1024 f32
  __hip_bfloat16* W2T     = (__hip_bfloat16*)alloc(1048576);  // 512x1024 bf16
  __hip_bfloat16* WloT    = (__hip_bfloat16*)alloc(10289152); // 10048x512 bf16
  float*          ET      = (float*)alloc(4063232);           // 31x512x64 f32
  __hip_bfloat16* Erow    = (__hip_bfloat16*)alloc(2031616);  // 1984x512 bf16
  __hip_bfloat16* HZ      = (__hip_bfloat16*)alloc(4063232);  // 1984x1024 bf16
  __hip_bfloat16* Ubf     = (__hip_bfloat16*)alloc(2031616);  // 1984x512 bf16
  float*          hT      = (float*)alloc(131072);            // 512x64 f32
  float*          cT      = (float*)alloc(131072);
  float*          zT      = (float*)alloc(131072);
  float*          ph1T    = (float*)alloc(786432);            // 3072x64 f32

  // ---- one-time conversions / transposes (run every launch; ws is re-poisoned) ----
  k_cast<<<dim3(6272), dim3(256), 0, stream>>>(enc, enc_bf, 1605632);
  k_trans_f32<<<dim3(16, 16), dim3(1024), 0, stream>>>(W_da, W1T,             512, 512,  512);
  k_trans_f32<<<dim3(16, 16), dim3(1024), 0, stream>>>(W_fb, W1T + 512*512,   512, 512,  512);
  k_trans_f32<<<dim3(64, 16), dim3(1024), 0, stream>>>(W_hh, W1T + 1024*512,  512, 2048, 512);
  k_trans_f32<<<dim3(64, 32), dim3(1024), 0, stream>>>(W_ih, WihT,           1024, 2048, 1024);
  k_trans_bf16<<<dim3(16, 16), dim3(1024), 0, stream>>>(W_ea, WeaT,       512, 512,   512,  512);
  k_trans_bf16<<<dim3(16, 16), dim3(1024), 0, stream>>>(W_lh, W2T,        512, 512,   1024, 512);
  k_trans_bf16<<<dim3(16, 16), dim3(1024), 0, stream>>>(W_lz, W2T + 512,  512, 512,   1024, 512);
  k_trans_bf16<<<dim3(314, 16), dim3(1024), 0, stream>>>(W_lo, WloT,      512, 10000, 512,  10048);
  k_emb<<<dim3(1984), dim3(512), 0, stream>>>(captions, emb, ET, Erow);
  k_init<<<dim3(64), dim3(512), 0, stream>>>(enc, W_hi, b_hi, W_ci, b_ci, hT, cT);

  // att1 = enc @ W_ea + b_ea  (bf16 out), M=12544, N=512, K=512
  k_gemm<<<dim3(8, 196), dim3(256), 0, stream>>>(enc_bf, WeaT, 512, 0, 512,
      b_ea, nullptr, nullptr, nullptr, att1_bf, nullptr);

  // ---- recurrent loop ----
  for (int t = 0; t < T_; t++){
    k_phase1<<<dim3(192), dim3(256), 0, stream>>>(hT, W1T, b_da, b_fb, ph1T);
    k_attn<<<dim3(64), dim3(256), 0, stream>>>(enc, att1_bf, ph1T, w_fa, caplen, t,
        zT, HZ, out + PRED_);
    k_gates<<<dim3(256), dim3(256), 0, stream>>>(ET, zT, WihT, ph1T, b_ih, b_hh,
        caplen, t, hT, cT, HZ);
  }

  // U = Erow + HZ @ [W_lh; W_lz] + b_lh + b_lz   (M=1984, N=512, K=1024)
  k_gemm<<<dim3(8, 31), dim3(256), 0, stream>>>(HZ, W2T, 1024, 1, 512,
      b_lh, b_lz, Erow, nullptr, Ubf, nullptr);
  // logits = U @ W_lo + b_lo  (masked), M=1984, N=10048 (10000 real), K=512
  k_gemm<<<dim3(157, 31), dim3(256), 0, stream>>>(Ubf, WloT, 512, 2, 10000,
      b_lo, nullptr, nullptr, caplen, nullptr, out);
}